// Round 4
// baseline (703.725 us; speedup 1.0000x reference)
//
#include <hip/hip_runtime.h>
#include <stdint.h>

#define B_DIM 4096
#define DIN   2048
#define UNITS 2048
#define KDIM  4096   // DIN + UNITS
#define BK2   32     // k per stage (per-wave double-buffered)

using s8v = __attribute__((ext_vector_type(8))) short;   // 8 x bf16 (4 VGPRs)
using f4v = __attribute__((ext_vector_type(4))) float;   // 4 x f32 acc

__device__ __forceinline__ unsigned short f2bf(float f) {
    union { float f; unsigned u; } v; v.f = f;
    unsigned u = v.u;
    unsigned r = u + 0x7FFFu + ((u >> 16) & 1u);   // RNE
    return (unsigned short)(r >> 16);
}

__device__ __forceinline__ void gl2lds16(const unsigned short* g, void* l) {
    __builtin_amdgcn_global_load_lds(
        (const __attribute__((address_space(1))) unsigned int*)g,
        (__attribute__((address_space(3))) unsigned int*)l, 16, 0, 0);
}

// explicit per-wave DMA->ds_read dependency waits (compiler does NOT insert
// these for global_load_lds -> ds_read without a barrier; R3 raced -> NaN)
#define WAIT_VM(n) asm volatile("s_waitcnt vmcnt(" #n ")" ::: "memory")

// ---------------- fused pack: z = [x|h] -> bf16, W -> bf16 transposed ----------------
#define NZ_BLOCKS 8192
__global__ __launch_bounds__(256) void pack_all(
    const float* __restrict__ x, const float* __restrict__ h,
    const float* __restrict__ Wf, const float* __restrict__ Wi,
    const float* __restrict__ Wc, const float* __restrict__ Wo,
    unsigned short* __restrict__ zA, unsigned short* __restrict__ WB) {
    __shared__ unsigned short T[64][68];   // +4 pad breaks bank collisions
    int t = threadIdx.x;
    int b = blockIdx.x;
    if (b < NZ_BLOCKS) {
        int ch  = b * 256 + t;              // 8-elem chunks, 512/row
        int m   = ch >> 9;
        int pos = (ch & 511) * 8;
        const float* src = (pos < DIN) ? (x + (size_t)m * DIN + pos)
                                       : (h + (size_t)m * UNITS + (pos - DIN));
        float4 v0 = *(const float4*)(src);
        float4 v1 = *(const float4*)(src + 4);
        s8v o;
        o[0]=f2bf(v0.x); o[1]=f2bf(v0.y); o[2]=f2bf(v0.z); o[3]=f2bf(v0.w);
        o[4]=f2bf(v1.x); o[5]=f2bf(v1.y); o[6]=f2bf(v1.z); o[7]=f2bf(v1.w);
        *(s8v*)(zA + (size_t)ch * 8) = o;
        return;
    }
    int bb = b - NZ_BLOCKS;
    int g   = bb >> 11;           // 2048 blocks per gate
    int rem = bb & 2047;
    int kt  = rem & 63, ut = rem >> 6;
    const float* Wg = (g == 0) ? Wf : (g == 1) ? Wi : (g == 2) ? Wc : Wo;
    int k0 = kt * 64, u0 = ut * 64;
    #pragma unroll
    for (int p = 0; p < 4; ++p) {
        int kl = p * 16 + (t >> 4);
        int ul = (t & 15) * 4;
        float4 v = *(const float4*)(Wg + (size_t)(k0 + kl) * UNITS + u0 + ul);
        T[kl][ul+0] = f2bf(v.x); T[kl][ul+1] = f2bf(v.y);
        T[kl][ul+2] = f2bf(v.z); T[kl][ul+3] = f2bf(v.w);
    }
    __syncthreads();
    #pragma unroll
    for (int p = 0; p < 2; ++p) {
        int s  = p * 256 + t;
        int ul = s >> 3;
        int kl = (s & 7) * 8;
        s8v o;
        #pragma unroll
        for (int j = 0; j < 8; ++j) o[j] = (short)T[kl + j][ul];
        *(s8v*)(WB + (size_t)(g * UNITS + u0 + ul) * KDIM + k0 + kl) = o;
    }
}

// ---------------- fused GEMM + LSTM epilogue, barrier-free K-loop ----------------
// block: 128 m x (4 gates x 32 u) as 4 waves of 64x64 tiles, each with a
// PRIVATE double-buffered 16 KB LDS slice -> no __syncthreads in the K-loop.
// DMA->ds_read ordering enforced by explicit s_waitcnt vmcnt(8/0).
__global__ __launch_bounds__(256) void lstm_gemm(
    const unsigned short* __restrict__ zA,   // 4096 x 4096 bf16
    const unsigned short* __restrict__ WB,   // 8192 x 4096 bf16, row n=g*2048+u
    const float* __restrict__ cin,
    const float* __restrict__ bfp, const float* __restrict__ bip,
    const float* __restrict__ bcp, const float* __restrict__ bop,
    float* __restrict__ out) {
    __shared__ unsigned char SM[65536];      // 4 waves x 16 KB; reused as E

    const int t    = threadIdx.x;
    const int lane = t & 63;
    const int wave = t >> 6;
    const int wm = wave >> 1, wn = wave & 1;
    const int q  = lane >> 4;     // k-quarter within 32-k frag
    const int fr = lane & 15;     // row within frag

    // XCD-aware swizzle: 4 m-tiles per XCD (4 MB A band stays in that XCD's L2)
    const int bid = blockIdx.x;
    const int xcd = bid & 7, local = bid >> 3;
    const int mt = xcd * 4 + (local & 3);
    const int ut = local >> 2;
    const int m0 = mt * 128;
    const int u0 = ut * 32;

    // per-wave staging: tile 64 rows x 32 k = 4 KB = 4 calls x (64 lanes x 16 B).
    // call j, lane l -> slot s=j*64+l at byte s*16 (row r=s>>2... see swizzle):
    // row r=j*16+(l>>2), phys chunk l&3 holds logical chunk (l&3)^(r&3).
    const int rl = lane >> 2;
    const int cl = lane & 3;
    const unsigned short* gA[4];
    const unsigned short* gB[4];
    #pragma unroll
    for (int j = 0; j < 4; ++j) {
        int r = j * 16 + rl;
        int c = cl ^ (r & 3);
        gA[j] = zA + (size_t)(m0 + wm * 64 + r) * KDIM + c * 8;
        int vn = wn * 64 + r;                       // virtual col in [0,128)
        int row = (vn >> 5) * UNITS + u0 + (vn & 31);
        gB[j] = WB + (size_t)row * KDIM + c * 8;
    }

    unsigned char* wb = SM + wave * 16384;   // stage p: A @ p*8192, B @ p*8192+4096

    // fragment LDS byte offsets (within a stage), same swizzle
    int offA[4], offB[4];
    #pragma unroll
    for (int i = 0; i < 4; ++i) {
        offA[i] = ((i * 16 + fr) * 4 + (q ^ (fr & 3))) * 16;
        offB[i] = 4096 + offA[i];
    }

    f4v acc[4][4];
    #pragma unroll
    for (int i = 0; i < 4; ++i)
        #pragma unroll
        for (int j = 0; j < 4; ++j) acc[i][j] = (f4v){0.f, 0.f, 0.f, 0.f};

    #define STAGE(P)                                                          \
        {                                                                     \
            _Pragma("unroll")                                                 \
            for (int j = 0; j < 4; ++j) {                                     \
                gl2lds16(gA[j], wb + (P) * 8192 + j * 1024);                  \
                gl2lds16(gB[j], wb + (P) * 8192 + 4096 + j * 1024);           \
                gA[j] += BK2; gB[j] += BK2;                                   \
            }                                                                 \
        }
    #define COMPUTE(P)                                                        \
        {                                                                     \
            s8v a_[4], b_[4];                                                 \
            _Pragma("unroll")                                                 \
            for (int i = 0; i < 4; ++i)                                       \
                a_[i] = *(const s8v*)(wb + (P) * 8192 + offA[i]);             \
            _Pragma("unroll")                                                 \
            for (int j = 0; j < 4; ++j)                                       \
                b_[j] = *(const s8v*)(wb + (P) * 8192 + offB[j]);             \
            _Pragma("unroll")                                                 \
            for (int i = 0; i < 4; ++i)                                       \
                _Pragma("unroll")                                             \
                for (int j = 0; j < 4; ++j)                                   \
                    acc[i][j] = __builtin_amdgcn_mfma_f32_16x16x32_bf16(      \
                        a_[i], b_[j], acc[i][j], 0, 0, 0);                    \
        }

    STAGE(0)                       // k-stage 0 -> buf 0   (8 loads in flight)
    #pragma unroll 1
    for (int it = 0; it < 64; ++it) {
        STAGE(1)                   // prefetch next stage into buf 1
        WAIT_VM(8);                // buf-0's 8 DMAs landed; buf-1's may fly
        COMPUTE(0)
        if (it != 63) {
            STAGE(0)
            WAIT_VM(8);            // buf-1's 8 DMAs landed
        } else {
            WAIT_VM(0);
        }
        COMPUTE(1)
    }
    #undef STAGE
    #undef COMPUTE

    __syncthreads();   // all waves done with private buffers before E reuse

    // ---- fused epilogue: per 32-row m-chunk, gates -> LDS -> activations ----
    float* E = (float*)SM;                       // 32 x 128 f32 = 16 KB
    float* outh = out;
    float* outc = out + (size_t)B_DIM * UNITS;
    #pragma unroll
    for (int chk = 0; chk < 4; ++chk) {
        if (wm == (chk >> 1)) {
            const int i0 = (chk & 1) * 2;
            #pragma unroll
            for (int ii = 0; ii < 2; ++ii) {
                #pragma unroll
                for (int j = 0; j < 4; ++j) {
                    int col = wn * 64 + j * 16 + fr;       // n_virt = gate*32+u
                    #pragma unroll
                    for (int p = 0; p < 4; ++p) {
                        int mc = ii * 16 + q * 4 + p;      // C row = q*4+p
                        E[mc * 128 + col] = acc[i0 + ii][j][p];
                    }
                }
            }
        }
        __syncthreads();
        #pragma unroll
        for (int v = 0; v < 4; ++v) {
            int idx = v * 256 + t;
            int mc = idx >> 5;
            int ul = idx & 31;
            float F = E[mc * 128 +       ul] + bfp[u0 + ul];
            float I = E[mc * 128 +  32 + ul] + bip[u0 + ul];
            float G = E[mc * 128 +  64 + ul] + bcp[u0 + ul];
            float O = E[mc * 128 +  96 + ul] + bop[u0 + ul];
            int m = m0 + chk * 32 + mc;
            float cv = cin[(size_t)m * UNITS + u0 + ul];
            float fg = 1.f / (1.f + __expf(-F));
            float ig = 1.f / (1.f + __expf(-I));
            float gg = 1.f - 2.f / (1.f + __expf(2.f * G));   // tanh, inf-safe
            float og = 1.f / (1.f + __expf(-O));
            float nc = fg * cv + ig * gg;
            float nh = og * (1.f - 2.f / (1.f + __expf(2.f * nc)));
            outc[(size_t)m * UNITS + u0 + ul] = nc;
            outh[(size_t)m * UNITS + u0 + ul] = nh;
        }
        __syncthreads();
    }
}

extern "C" void kernel_launch(void* const* d_in, const int* in_sizes, int n_in,
                              void* d_out, int out_size, void* d_ws, size_t ws_size,
                              hipStream_t stream) {
    const float* x  = (const float*)d_in[0];
    const float* h  = (const float*)d_in[1];
    const float* c  = (const float*)d_in[2];
    const float* Wf = (const float*)d_in[3];
    const float* bf = (const float*)d_in[4];
    const float* Wi = (const float*)d_in[5];
    const float* bi = (const float*)d_in[6];
    const float* Wc = (const float*)d_in[7];
    const float* bc = (const float*)d_in[8];
    const float* Wo = (const float*)d_in[9];
    const float* bo = (const float*)d_in[10];

    unsigned short* zA = (unsigned short*)d_ws;                 // 32 MB
    unsigned short* WB = zA + (size_t)B_DIM * KDIM;             // 64 MB

    pack_all<<<2 * NZ_BLOCKS, 256, 0, stream>>>(x, h, Wf, Wi, Wc, Wo, zA, WB);
    lstm_gemm<<<(B_DIM / 128) * (UNITS / 32), 256, 0, stream>>>(
        zA, WB, c, bf, bi, bc, bo, (float*)d_out);
}